// Round 1
// baseline (4295.336 us; speedup 1.0000x reference)
//
#include <hip/hip_runtime.h>

#define U 128
#define AP 136  // LDS pitch in bf16 elements (128 + 8 pad -> conflict-free ds_read_b128)

typedef short bf16x8 __attribute__((ext_vector_type(8)));
typedef float f4v __attribute__((ext_vector_type(4)));

__device__ __forceinline__ unsigned f2b_u(float f) {
    union { float f; unsigned u; } v; v.f = f;
    return (v.u + 0x7fffu + ((v.u >> 16) & 1u)) >> 16;  // RNE fp32 -> bf16
}
__device__ __forceinline__ unsigned short f2b(float f) { return (unsigned short)f2b_u(f); }
__device__ __forceinline__ float b2f(unsigned short s) {
    union { unsigned u; float f; } v; v.u = ((unsigned)s) << 16;
    return v.f;
}
__device__ __forceinline__ int4 pack8(float4 a, float4 b) {
    int4 r;
    r.x = (int)(f2b_u(a.x) | (f2b_u(a.y) << 16));
    r.y = (int)(f2b_u(a.z) | (f2b_u(a.w) << 16));
    r.z = (int)(f2b_u(b.x) | (f2b_u(b.y) << 16));
    r.w = (int)(f2b_u(b.z) | (f2b_u(b.w) << 16));
    return r;
}
__device__ __forceinline__ float fast_tanh(float x) {
    x = fminf(fmaxf(x, -15.f), 15.f);
    float t = __expf(2.f * x);
    return (t - 1.f) / (t + 1.f);
}

// ---- MFMA over a staged 128x128 A-tile and 128x128 B-tile (Bs holds B^T) ----
__device__ __forceinline__ void mfma_block(const unsigned short* As, const unsigned short* Bs,
                                           f4v acc[4][4], int lane, int wr, int wc)
{
    const int m = lane & 15;
    const int q = (lane >> 4) * 8;
    #pragma unroll
    for (int ks = 0; ks < 4; ++ks) {
        bf16x8 af[4], bf[4];
        #pragma unroll
        for (int i = 0; i < 4; ++i)
            af[i] = *(const bf16x8*)(As + (wr * 64 + i * 16 + m) * AP + ks * 32 + q);
        #pragma unroll
        for (int j = 0; j < 4; ++j)
            bf[j] = *(const bf16x8*)(Bs + (wc * 64 + j * 16 + m) * AP + ks * 32 + q);
        #pragma unroll
        for (int i = 0; i < 4; ++i) {
            #pragma unroll
            for (int j = 0; j < 4; ++j) {
                acc[i][j] = __builtin_amdgcn_mfma_f32_16x16x32_bf16(af[i], bf[j], acc[i][j], 0, 0, 0);
            }
        }
    }
}

// Fused (gather/concat) -> Linear(K1,U) -> tanh -> Linear(U,U) kernel.
// Tile: 128 rows x 128 cols per block (256 threads / 4 waves, each wave 64x64).
// Chunk c of the K1 concat dim:
//   c==0: "self" rows (fp32 inputs for up-stages, bf16 ws for dn-stages)
//   c>=1: GATHER ? gathered bf16 rows via idx : fp32 hd accumulator rows
template <int NCHUNK, bool SELF_F32, bool GATHER, bool OUT_F32>
__global__ __launch_bounds__(256, 2)
void mlp_kernel(const void* __restrict__ self_,
                const unsigned short* __restrict__ gsrc,
                const float* __restrict__ hd,
                const int* __restrict__ idx,
                const unsigned short* __restrict__ W1T,  // [128][NCHUNK*128] bf16 (W1 transposed)
                const float* __restrict__ b1,
                const unsigned short* __restrict__ W2T,  // [128][128] bf16 (W2 transposed)
                const float* __restrict__ b2,
                void* __restrict__ out_)
{
    __shared__ __align__(16) unsigned short As[128 * AP];
    __shared__ __align__(16) unsigned short Bs[128 * AP];
    __shared__ int lidx[256];

    const int tid = (int)threadIdx.x;
    const long r0 = (long)blockIdx.x * 128;
    const int lane = tid & 63;
    const int wave = tid >> 6;
    const int wr = wave >> 1;
    const int wc = wave & 1;
    const int trow = tid >> 4;   // 0..15
    const int tcol = tid & 15;   // 0..15 (16B chunk within a 256B row)

    if constexpr (GATHER) {
        lidx[tid] = idx[r0 * 2 + tid];
    }

    f4v acc[4][4];
    #pragma unroll
    for (int i = 0; i < 4; ++i) {
        #pragma unroll
        for (int j = 0; j < 4; ++j) acc[i][j] = f4v{0.f, 0.f, 0.f, 0.f};
    }

    #pragma unroll
    for (int c = 0; c < NCHUNK; ++c) {
        __syncthreads();  // protect As/Bs from previous chunk's readers (also fences lidx at c==0)
        #pragma unroll
        for (int it = 0; it < 8; ++it) {
            const int r = it * 16 + trow;
            int4 v;
            if (c == 0) {
                if constexpr (SELF_F32) {
                    const float* src = (const float*)self_ + (r0 + r) * (long)U;
                    v = pack8(((const float4*)src)[tcol * 2], ((const float4*)src)[tcol * 2 + 1]);
                } else {
                    v = ((const int4*)((const unsigned short*)self_ + (r0 + r) * (long)U))[tcol];
                }
            } else if constexpr (GATHER) {
                const long g = lidx[r * 2 + (c - 1)];
                v = ((const int4*)(gsrc + g * (long)U))[tcol];
            } else {
                const float* src = hd + (r0 + r) * (long)U;
                v = pack8(((const float4*)src)[tcol * 2], ((const float4*)src)[tcol * 2 + 1]);
            }
            *(int4*)(As + r * AP + tcol * 8) = v;
            // stage weight chunk: Bs[n][k] = W1T[n][c*128+k]
            const int4 wv = ((const int4*)(W1T + (long)r * (NCHUNK * 128) + c * 128))[tcol];
            *(int4*)(Bs + r * AP + tcol * 8) = wv;
        }
        __syncthreads();
        mfma_block(As, Bs, acc, lane, wr, wc);
    }

    __syncthreads();  // all waves done reading As/Bs of last chunk
    {
        // epilogue 1: +b1, tanh, write bf16 back into As; stage W2T into Bs
        const int m = lane & 15;
        const int qr = (lane >> 4) * 4;
        float bv[4];
        #pragma unroll
        for (int j = 0; j < 4; ++j) bv[j] = b1[wc * 64 + j * 16 + m];
        #pragma unroll
        for (int i = 0; i < 4; ++i) {
            #pragma unroll
            for (int j = 0; j < 4; ++j) {
                #pragma unroll
                for (int rr = 0; rr < 4; ++rr) {
                    const float v = acc[i][j][rr] + bv[j];
                    As[(wr * 64 + i * 16 + qr + rr) * AP + wc * 64 + j * 16 + m] = f2b(fast_tanh(v));
                    acc[i][j][rr] = 0.f;
                }
            }
        }
        #pragma unroll
        for (int it = 0; it < 8; ++it) {
            const int r = it * 16 + trow;
            *(int4*)(Bs + r * AP + tcol * 8) = ((const int4*)(W2T + r * 128))[tcol];
        }
    }
    __syncthreads();
    mfma_block(As, Bs, acc, lane, wr, wc);
    {
        // epilogue 2: +b2, store
        const int m = lane & 15;
        const int qr = (lane >> 4) * 4;
        float bv[4];
        #pragma unroll
        for (int j = 0; j < 4; ++j) bv[j] = b2[wc * 64 + j * 16 + m];
        #pragma unroll
        for (int i = 0; i < 4; ++i) {
            #pragma unroll
            for (int j = 0; j < 4; ++j) {
                #pragma unroll
                for (int rr = 0; rr < 4; ++rr) {
                    const float v = acc[i][j][rr] + bv[j];
                    const long orow = r0 + wr * 64 + i * 16 + qr + rr;
                    const int ocol = wc * 64 + j * 16 + m;
                    if constexpr (OUT_F32)
                        ((float*)out_)[orow * (long)U + ocol] = v;
                    else
                        ((unsigned short*)out_)[orow * (long)U + ocol] = f2b(v);
                }
            }
        }
    }
}

// fp32 -> bf16 elementwise (8 elems/thread)
__global__ void cvt_kernel(const float* __restrict__ in, unsigned short* __restrict__ out) {
    const long t = ((long)blockIdx.x * 256 + threadIdx.x) * 8;
    float4 a = ((const float4*)(in + t))[0];
    float4 b = ((const float4*)(in + t))[1];
    *(int4*)(out + t) = pack8(a, b);
}

// segment-sum via atomics: thread = (parent row, element)
__global__ void scatter_kernel(const unsigned short* __restrict__ src,
                               const int* __restrict__ idx,
                               float* __restrict__ dst)
{
    const long t = (long)blockIdx.x * 256 + threadIdx.x;
    const long row = t >> 7;
    const int e = (int)(t & 127);
    const float v = b2f(src[row * (long)U + e]);
    const int c0 = idx[row * 2];
    const int c1 = idx[row * 2 + 1];
    atomicAdd(dst + (long)c0 * U + e, v);
    atomicAdd(dst + (long)c1 * U + e, v);
}

struct WDesc { const float* src; unsigned short* dst; int K; };
struct WPack { WDesc w[12]; };

// transpose fp32 W[K][128] -> bf16 WT[128][K]
__global__ void prep_kernel(WPack p) {
    const int stride = gridDim.x * 256;
    const int t0 = blockIdx.x * 256 + threadIdx.x;
    for (int wi = 0; wi < 12; ++wi) {
        const float* src = p.w[wi].src;
        unsigned short* dst = p.w[wi].dst;
        const int K = p.w[wi].K;
        const int total = K * 128;
        for (int i = t0; i < total; i += stride) {
            const int n = i / K;
            const int k = i - n * K;
            dst[i] = f2b(src[(long)k * 128 + n]);
        }
    }
}

extern "C" void kernel_launch(void* const* d_in, const int* in_sizes, int n_in,
                              void* d_out, int out_size, void* d_ws, size_t ws_size,
                              hipStream_t stream)
{
    (void)in_sizes; (void)n_in; (void)out_size; (void)ws_size;
    const float* h1 = (const float*)d_in[0];
    const float* h2 = (const float*)d_in[1];
    const float* h3 = (const float*)d_in[2];
    const float* h4 = (const float*)d_in[3];
    const int* idx2 = (const int*)d_in[4];
    const int* idx3 = (const int*)d_in[5];
    const int* idx4 = (const int*)d_in[6];
    const float* up2_W1 = (const float*)d_in[7];
    const float* up2_b1 = (const float*)d_in[8];
    const float* up2_W2 = (const float*)d_in[9];
    const float* up2_b2 = (const float*)d_in[10];
    const float* up3_W1 = (const float*)d_in[11];
    const float* up3_b1 = (const float*)d_in[12];
    const float* up3_W2 = (const float*)d_in[13];
    const float* up3_b2 = (const float*)d_in[14];
    const float* up4_W1 = (const float*)d_in[15];
    const float* up4_b1 = (const float*)d_in[16];
    const float* up4_W2 = (const float*)d_in[17];
    const float* up4_b2 = (const float*)d_in[18];
    const float* dn1_W1 = (const float*)d_in[19];
    const float* dn1_b1 = (const float*)d_in[20];
    const float* dn1_W2 = (const float*)d_in[21];
    const float* dn1_b2 = (const float*)d_in[22];
    const float* dn2_W1 = (const float*)d_in[23];
    const float* dn2_b1 = (const float*)d_in[24];
    const float* dn2_W2 = (const float*)d_in[25];
    const float* dn2_b2 = (const float*)d_in[26];
    const float* dn3_W1 = (const float*)d_in[27];
    const float* dn3_b1 = (const float*)d_in[28];
    const float* dn3_W2 = (const float*)d_in[29];
    const float* dn3_b2 = (const float*)d_in[30];

    char* ws = (char*)d_ws;
    // weight pool (bf16, transposed): 12 matrices
    const size_t woff[12] = {0, 98304, 196608, 294912, 360448, 425984,
                             491520, 524288, 557056, 589824, 622592, 655360};
    unsigned short* wT[12];
    for (int i = 0; i < 12; ++i) wT[i] = (unsigned short*)(ws + woff[i]);

    // activation pools (bf16 ws = 2B/elem, hd accumulators fp32 = 4B/elem)
    unsigned short* h1b = (unsigned short*)(ws + 1048576);     // 102.4 MB
    unsigned short* h2b = (unsigned short*)(ws + 103448576);   // 102.4 MB
    unsigned short* h3b = (unsigned short*)(ws + 205848576);   // 204.8 MB
    unsigned short* h4b = (unsigned short*)(ws + 410648576);   // P4: 307.2 MB
    unsigned short* h3c = h4b;                                 // reuse P4 after scatter3
    float* hd3f = (float*)(ws + 717848576);                    // P5: 409.6 MB
    float* hd2f = hd3f;                                        // reuse P5 after dn3
    unsigned short* h2c = (unsigned short*)(ws + 922648576);   // P5 tail
    float* hd1f = (float*)(ws + 205848576);                    // reuse h3b after dn3

    WPack wp;
    const float* w1s[6] = {up2_W1, up3_W1, up4_W1, dn1_W1, dn2_W1, dn3_W1};
    const float* w2s[6] = {up2_W2, up3_W2, up4_W2, dn1_W2, dn2_W2, dn3_W2};
    for (int i = 0; i < 6; ++i) { wp.w[i].src = w1s[i]; wp.w[i].dst = wT[i]; wp.w[i].K = (i < 3) ? 384 : 256; }
    for (int i = 0; i < 6; ++i) { wp.w[6 + i].src = w2s[i]; wp.w[6 + i].dst = wT[6 + i]; wp.w[6 + i].K = 128; }

    hipLaunchKernelGGL(prep_kernel, dim3(1344), dim3(256), 0, stream, wp);
    hipLaunchKernelGGL(cvt_kernel, dim3(25000), dim3(256), 0, stream, h1, h1b);

    // ---- upward ----
    hipLaunchKernelGGL((mlp_kernel<3, true, true, false>), dim3(3125), dim3(256), 0, stream,
                       (const void*)h2, (const unsigned short*)h1b, (const float*)nullptr, idx2,
                       (const unsigned short*)wT[0], up2_b1, (const unsigned short*)wT[6], up2_b2, (void*)h2b);
    hipLaunchKernelGGL((mlp_kernel<3, true, true, false>), dim3(6250), dim3(256), 0, stream,
                       (const void*)h3, (const unsigned short*)h2b, (const float*)nullptr, idx3,
                       (const unsigned short*)wT[1], up3_b1, (const unsigned short*)wT[7], up3_b2, (void*)h3b);
    hipLaunchKernelGGL((mlp_kernel<3, true, true, false>), dim3(9375), dim3(256), 0, stream,
                       (const void*)h4, (const unsigned short*)h3b, (const float*)nullptr, idx4,
                       (const unsigned short*)wT[2], up4_b1, (const unsigned short*)wT[8], up4_b2, (void*)h4b);

    // ---- downward: level 3 ----
    hipMemsetAsync(hd3f, 0, 409600000, stream);
    hipLaunchKernelGGL(scatter_kernel, dim3(600000), dim3(256), 0, stream,
                       (const unsigned short*)h4b, idx4, hd3f);
    hipLaunchKernelGGL((mlp_kernel<2, false, false, false>), dim3(6250), dim3(256), 0, stream,
                       (const void*)h3b, (const unsigned short*)nullptr, (const float*)hd3f, (const int*)nullptr,
                       (const unsigned short*)wT[5], dn3_b1, (const unsigned short*)wT[11], dn3_b2, (void*)h3c);

    // ---- downward: level 2 ----
    hipMemsetAsync(hd2f, 0, 204800000, stream);
    hipLaunchKernelGGL(scatter_kernel, dim3(400000), dim3(256), 0, stream,
                       (const unsigned short*)h3c, idx3, hd2f);
    hipLaunchKernelGGL((mlp_kernel<2, false, false, false>), dim3(3125), dim3(256), 0, stream,
                       (const void*)h2b, (const unsigned short*)nullptr, (const float*)hd2f, (const int*)nullptr,
                       (const unsigned short*)wT[4], dn2_b1, (const unsigned short*)wT[10], dn2_b2, (void*)h2c);

    // ---- downward: level 1 ----
    hipMemsetAsync(hd1f, 0, 204800000, stream);
    hipLaunchKernelGGL(scatter_kernel, dim3(200000), dim3(256), 0, stream,
                       (const unsigned short*)h2c, idx2, hd1f);
    hipLaunchKernelGGL((mlp_kernel<2, false, false, true>), dim3(3125), dim3(256), 0, stream,
                       (const void*)h1b, (const unsigned short*)nullptr, (const float*)hd1f, (const int*)nullptr,
                       (const unsigned short*)wT[3], dn1_b1, (const unsigned short*)wT[9], dn1_b2, d_out);
}